// Round 2
// baseline (603.913 us; speedup 1.0000x reference)
//
#include <hip/hip_runtime.h>
#include <math.h>

#define N      96
#define NN     9216
#define LAT    256
#define ODIM   4656
#define CH     128      // k-chunks for encoder GEMV partials
#define RPC    72       // rows per chunk (128*72 = 9216)
#define ITERS  50
#define CB     48       // persistent mpm blocks (2 output columns each)
#define CT     192      // threads per mpm block
#define XPAD   100      // LDS row pad for x

// ---- workspace layout (float offsets) ----
#define WS_PART 0                       // [2][CH][LAT] = 65536
#define WS_OUTS 65536                   // 4656 sigmoid outputs
#define WS_KL   70192                   // 1
#define WS_BCE  70193                   // 1 (atomic accumulator)
#define WS_CTR  70194                   // 1 (barrier counter, as unsigned)
#define WS_NORM 70196                   // slots [1..50] used
#define WS_AOFT 70272                   // 9216 (Aoff transposed: [j][i])
#define WS_BOFF 79488                   // 9216 ([a][b])
#define WS_SDT  88704                   // 9216 (Sd transposed: [a][i])
#define WS_XB   97920                   // 2 x 9216 ping-pong

__device__ __forceinline__ int tri(int i, int j) {   // i <= j
    return i * N - i * (i - 1) / 2 + (j - i);
}

__device__ __forceinline__ int tri_row(int o) {
    int i = (int)floorf((193.0f - sqrtf((float)(37249 - 8 * o))) * 0.5f);
    i = max(0, min(95, i));
    while ((i + 1) * N - (i + 1) * i / 2 <= o) ++i;
    while (i * N - i * (i - 1) / 2 > o) --i;
    return i;
}

// ---- kA: encoder GEMV partials + control-word zeroing ----
__global__ __launch_bounds__(256) void kA_gemv(const float* __restrict__ h,
                                               const float* __restrict__ W1,
                                               const float* __restrict__ W2,
                                               float* __restrict__ ws) {
    __shared__ float hs[RPC];
    int t = threadIdx.x, c = blockIdx.x;
    if (c == 0 && t < 64) ws[WS_BCE + t] = 0.f;   // BCE, barrier ctr, norm slots
    int k0 = c * RPC;
    if (t < RPC) hs[t] = h[k0 + t];
    __syncthreads();
    float a1 = 0.f, a2 = 0.f;
    #pragma unroll 4
    for (int kk = 0; kk < RPC; ++kk) {
        float hv = hs[kk];
        a1 = fmaf(hv, W1[(k0 + kk) * LAT + t], a1);
        a2 = fmaf(hv, W2[(k0 + kk) * LAT + t], a2);
    }
    ws[WS_PART + c * LAT + t]        = a1;
    ws[WS_PART + (CH + c) * LAT + t] = a2;
}

// ---- kB: reduce partials -> z ; KL ; decoder ; sigmoid ; BCE ----
__global__ __launch_bounds__(256) void kB_dec(const float* __restrict__ eps,
                                              const float* __restrict__ be11,
                                              const float* __restrict__ be12,
                                              const float* __restrict__ Wd1,
                                              const float* __restrict__ bd1,
                                              const float* __restrict__ Wd2,
                                              const float* __restrict__ bd2,
                                              const float* __restrict__ adj,
                                              float* __restrict__ ws) {
    __shared__ float zi[LAT];
    __shared__ float hid[LAT];
    __shared__ float red[256];
    int t = threadIdx.x;
    // redundant per-block reduction of encoder partials (L2-resident, cheap)
    const float* p = ws + WS_PART;
    float mu = 0.f, ls = 0.f;
    #pragma unroll 8
    for (int c = 0; c < CH; ++c) {
        mu += p[c * LAT + t];
        ls += p[(CH + c) * LAT + t];
    }
    mu += be11[t];
    ls += be12[t];
    zi[t] = eps[t] * expf(0.5f * ls) + mu;
    red[t] = 1.0f + ls - mu * mu - expf(ls);
    __syncthreads();
    for (int s = 128; s > 0; s >>= 1) {
        if (t < s) red[t] += red[t + s];
        __syncthreads();
    }
    if (blockIdx.x == 0 && t == 0) ws[WS_KL] = -0.5f * red[0] / 9216.0f;
    __syncthreads();
    // hidden = relu(z @ Wd1 + bd1), redundant per block
    float acc = 0.f;
    #pragma unroll 8
    for (int k = 0; k < LAT; ++k) acc = fmaf(zi[k], Wd1[k * LAT + t], acc);
    hid[t] = fmaxf(acc + bd1[t], 0.f);
    __syncthreads();
    // this block's slice of the 4656 outputs
    int o = blockIdx.x * 256 + t;
    float term = 0.f;
    if (o < ODIM) {
        float a2 = 0.f;
        #pragma unroll 8
        for (int k = 0; k < LAT; ++k) a2 = fmaf(hid[k], Wd2[k * ODIM + o], a2);
        float y = a2 + bd2[o];
        float s = 1.0f / (1.0f + expf(-y));
        ws[WS_OUTS + o] = s;
        int i = tri_row(o);
        int j = i + (o - (i * N - i * (i - 1) / 2));
        float inp = adj[i * N + j];
        float li = fmaxf(logf(inp), -100.0f);
        float l1 = fmaxf(log1pf(-inp), -100.0f);
        term = s * li + (1.0f - s) * l1;
    }
    red[t] = term;
    __syncthreads();
    for (int s = 128; s > 0; s >>= 1) {
        if (t < s) red[t] += red[t + s];
        __syncthreads();
    }
    if (t == 0) atomicAdd(ws + WS_BCE, red[0]);
}

// ---- device-scope grid barrier (monotonic counter) ----
__device__ __forceinline__ void gbar(unsigned* ctr, unsigned target) {
    __syncthreads();
    if (threadIdx.x == 0) {
        __threadfence();                              // release
        __hip_atomic_fetch_add(ctr, 1u, __ATOMIC_RELAXED, __HIP_MEMORY_SCOPE_AGENT);
        while (__hip_atomic_load(ctr, __ATOMIC_RELAXED, __HIP_MEMORY_SCOPE_AGENT) < target)
            __builtin_amdgcn_s_sleep(1);
        __threadfence();                              // acquire
    }
    __syncthreads();
}

// ---- kC: build Aoff/Boff/Sd, run all 50 MPM iterations, write output ----
__global__ __launch_bounds__(CT, 1) void kC_mpm(const float* __restrict__ adj,
                                                float* __restrict__ ws,
                                                float* __restrict__ out) {
    __shared__ float xn[N][XPAD];
    __shared__ float Brow[2][N];
    __shared__ float Scol[2][N];
    __shared__ float Mv[2][N];
    __shared__ float red[CT];
    __shared__ float ds[N], drs[N], ft[N], ftr[N];

    float* outs  = ws + WS_OUTS;
    float* AoffT = ws + WS_AOFT;
    float* Boff  = ws + WS_BOFF;
    float* SdT   = ws + WS_SDT;
    float* norm  = ws + WS_NORM;
    unsigned* ctr = (unsigned*)(ws + WS_CTR);

    int t  = threadIdx.x;
    int bid = blockIdx.x;
    int jj = t % N, al = t / N;
    int a0 = bid * 2;

    // ---- build phase (each block: shared scalars redundant, 192 entries of each matrix)
    if (t < N) {
        ds[t]  = adj[t * N + t];
        drs[t] = outs[tri(t, t)];
        float s1 = 0.f, s2 = 0.f;
        for (int b = 0; b < N; ++b) {
            s1 += adj[t * N + b];
            int lo = min(t, b), hi = max(t, b);
            s2 += outs[tri(lo, hi)];
        }
        ft[t] = s1; ftr[t] = s2;
    }
    __syncthreads();
    {
        int f = bid * CT + t;              // 48*192 = 9216, one entry per thread
        int i = f / N, j = f % N;
        AoffT[j * N + i] = (i == j) ? 0.f : (adj[f] * ds[i]) * ds[j];
        int lo = min(i, j), hi = max(i, j);
        AoffT[j * N + i] = (i == j) ? 0.f : (adj[f] * ds[i]) * ds[j];
        Boff[f] = (i == j) ? 0.f : (outs[tri(lo, hi)] * drs[i]) * drs[j];
        SdT[f]  = (ds[j] * drs[i]) * (1.0f / (fabsf(ft[j] - ftr[i]) + 1.0f));
    }
    gbar(ctr, 1u * CB);

    // per-block constants for the iteration loop
    Brow[al][jj] = Boff[(a0 + al) * N + jj];
    Scol[al][jj] = SdT[(a0 + al) * N + jj];
    __syncthreads();

    float acc = 0.f;
    for (int it = 0; it < ITERS; ++it) {
        // stage x (normalized) into LDS
        if (it == 0) {
            const float v0 = (float)(1.0 / 96.0);
            for (int f = t; f < NN; f += CT) xn[f / N][f % N] = v0;
        } else {
            float inv = 1.0f / sqrtf(norm[it]);
            const float4* src = (const float4*)(ws + WS_XB + ((it + 1) & 1) * NN);
            for (int q = t; q < NN / 4; q += CT) {
                float4 v = src[q];
                int f = q * 4;
                v.x *= inv; v.y *= inv; v.z *= inv; v.w *= inv;
                *(float4*)&xn[f / N][f % N] = v;
            }
        }
        __syncthreads();

        // phase B: M[j, a0+al] = max_b Boff[a0+al, b] * xn[j, b]
        float m = 0.f;
        #pragma unroll
        for (int bq = 0; bq < N / 4; ++bq) {
            float4 xv = *(const float4*)&xn[jj][bq * 4];
            m = fmaxf(m, Brow[al][bq * 4 + 0] * xv.x);
            m = fmaxf(m, Brow[al][bq * 4 + 1] * xv.y);
            m = fmaxf(m, Brow[al][bq * 4 + 2] * xv.z);
            m = fmaxf(m, Brow[al][bq * 4 + 3] * xv.w);
        }
        Mv[al][jj] = m;
        __syncthreads();

        // phase C: x_new[i, a0+al] = xn[i,a]*Sd + sum_j AoffT[j,i]*M[j,a]
        acc = xn[jj][a0 + al] * Scol[al][jj];
        #pragma unroll 8
        for (int j = 0; j < N; ++j)
            acc = fmaf(AoffT[j * N + jj], Mv[al][j], acc);
        if (it < ITERS - 1)
            ws[WS_XB + (it & 1) * NN + jj * N + (a0 + al)] = acc;

        // block partial of ||x_new||^2 -> norm[it+1]
        red[t] = acc * acc;
        __syncthreads();
        if (t < 96) red[t] += red[t + 96]; __syncthreads();
        if (t < 48) red[t] += red[t + 48]; __syncthreads();
        if (t < 24) red[t] += red[t + 24]; __syncthreads();
        if (t < 12) red[t] += red[t + 12]; __syncthreads();
        if (t < 6)  red[t] += red[t + 6];  __syncthreads();
        if (t == 0)
            atomicAdd(&norm[it + 1],
                      red[0] + red[1] + red[2] + red[3] + red[4] + red[5]);
        gbar(ctr, (unsigned)(it + 2) * CB);
    }

    // epilogue: final normalize from registers, write output
    float invf = 1.0f / sqrtf(norm[ITERS]);
    out[1 + jj * N + (a0 + al)] = acc * invf;
    if (bid == 0 && t == 0) out[0] = -(ws[WS_BCE] / 4656.0f) + ws[WS_KL];
}

extern "C" void kernel_launch(void* const* d_in, const int* in_sizes, int n_in,
                              void* d_out, int out_size, void* d_ws, size_t ws_size,
                              hipStream_t stream) {
    const float* inf  = (const float*)d_in[0];
    const float* adj  = (const float*)d_in[1];
    const float* eps  = (const float*)d_in[2];
    const float* We11 = (const float*)d_in[3];
    const float* be11 = (const float*)d_in[4];
    const float* We12 = (const float*)d_in[5];
    const float* be12 = (const float*)d_in[6];
    const float* Wd1  = (const float*)d_in[7];
    const float* bd1  = (const float*)d_in[8];
    const float* Wd2  = (const float*)d_in[9];
    const float* bd2  = (const float*)d_in[10];
    float* ws  = (float*)d_ws;
    float* out = (float*)d_out;

    kA_gemv<<<CH, 256, 0, stream>>>(inf, We11, We12, ws);
    kB_dec <<<19, 256, 0, stream>>>(eps, be11, be12, Wd1, bd1, Wd2, bd2, adj, ws);
    kC_mpm <<<CB, CT, 0, stream>>>(adj, ws, out);
}